// Round 8
// baseline (354.582 us; speedup 1.0000x reference)
//
#include <hip/hip_runtime.h>
#include <hip/hip_bf16.h>

using bf16 = __hip_bfloat16;
using bf16x8 = __attribute__((ext_vector_type(8))) short;  // 8 bf16 (4 VGPRs)
using f32x4  = __attribute__((ext_vector_type(4))) float;

#define NN 512
#define NS 511

// ---------------- workspace layout (float offsets) ----------------
// slot 0 holds the dtype flag (int: 0 = bf16 inputs, 1 = f32 inputs)
enum : int {
  WS_POS   = 16,       // [512][3] positions (updated in-place after layer 0)
  WS_TE    = 1552,     // [32]
  WS_WEMB  = 1584,     // [37][64]
  WS_BEMB  = 3952,     // [64]
  WS_WLIN  = 4016,     // [2][3][64][64]
  WS_WE1   = 28592,    // [2][1][32]
  WS_BE1   = 28656,    // [2][32]
  WS_WE2   = 28720,    // [2][32][384]
  WS_WP0   = 53296,    // [2][5][64][6]
  WS_WP1   = 57136,    // [2][5][64][3]
  WS_WR1   = 59056,    // [2][64][64]
  WS_BR1   = 67248,    // [2][64]
  WS_WR2G  = 67376,    // [2][64][64]
  WS_DELTA = 75568,    // [512][3] layer-0 displacement
  WS_XS    = 208176,   // [512][64][4] interleaved (x0, x1x, x1y, x1z) — 16B aligned
  WS_A     = 339248,   // [2][512][64][9] partial sums (sender halves)
};                      // end = 929072 floats ~= 3.72 MB

// exact RNE float->bf16 bits (no NaN inputs here)
__device__ __forceinline__ short f2b(float x) {
  unsigned u = __builtin_bit_cast(unsigned, x);
  unsigned r = (u + 0x7fffu + ((u >> 16) & 1u)) >> 16;
  return (short)r;
}

// ---------------- convert (detect fused): everything -> fp32 in ws ----------------
__global__ __launch_bounds__(256) void k_convert(
    const void* p0, const void* p1, const void* p2, const void* p3,
    const void* p4, const void* p5, const void* p6, const void* p7,
    const void* p8, const void* p9, const void* p10, const void* p11,
    const void* p12, const void* wembed, float* __restrict__ ws) {
  int t = threadIdx.x;
  // per-block dtype detection on W_embed's first 256 bf16-view elements:
  // true-bf16 -> ~256 sane magnitudes; f32-misread -> ~170 sane.
  const bf16* wp = (const bf16*)wembed;
  float v = __bfloat162float(wp[t]);
  float a = fabsf(v);
  int sane = (v == v && a > 1e-8f && a < 1e4f) ? 1 : 0;
  int cnt = __syncthreads_count(sane);
  int isf32 = (cnt >= 240) ? 0 : 1;
  if (blockIdx.x == 0 && t == 0) ((int*)ws)[0] = isf32;
  int idx = blockIdx.x * 256 + t;
  if (idx >= 75552) return;
  const int C[14] = {0, 1536, 1568, 3936, 4000, 28576, 28640, 28704,
                     53280, 57120, 59040, 67232, 67360, 75552};
  int s = 0;
  #pragma unroll
  for (int k = 1; k < 14; ++k) if (idx >= C[k]) s = k;
  int off = idx - C[s];
  const void* src;
  switch (s) {
    case 0:  src = p0;  break;  case 1:  src = p1;  break;
    case 2:  src = p2;  break;  case 3:  src = p3;  break;
    case 4:  src = p4;  break;  case 5:  src = p5;  break;
    case 6:  src = p6;  break;  case 7:  src = p7;  break;
    case 8:  src = p8;  break;  case 9:  src = p9;  break;
    case 10: src = p10; break;  case 11: src = p11; break;
    default: src = p12; break;
  }
  float v2;
  if (isf32) v2 = ((const float*)src)[off];
  else       v2 = __bfloat162float(((const bf16*)src)[off]);
  ws[WS_POS + idx] = v2;
}

// ---------------- embedding + layer-0 node linear (fused) ----------------
__global__ __launch_bounds__(64) void k_pre(const int* __restrict__ nodef,
                                            float* __restrict__ ws) {
  int n = blockIdx.x, f = threadIdx.x;
  int sp = nodef[n] - 1;
  const float* wemb = ws + WS_WEMB;
  const float* te = ws + WS_TE;
  float h = ws[WS_BEMB + f] + wemb[sp * 64 + f];
  #pragma unroll 8
  for (int q = 0; q < 32; ++q)
    h += te[q] * wemb[(5 + q) * 64 + f];
  __shared__ float hl[64];
  hl[f] = h;
  __syncthreads();
  const float* W0 = ws + WS_WLIN;  // layer0, path0
  float a0 = 0.f;
  #pragma unroll 8
  for (int q = 0; q < 64; ++q)
    a0 += hl[q] * W0[q * 64 + f];
  f32x4 o = {a0, 0.f, 0.f, 0.f};
  *(f32x4*)&ws[WS_XS + (n * 64 + f) * 4] = o;
}

// ---------------- fused edge + aggregate (MFMA, low-register) ----------------
// Grid 1024 = 512 receivers x 2 sender-halves; 256 threads (4 waves).
// Register diet vs r4/r7 (which spilled ~230 demanded regs into scratch,
// the 90-126 MB FETCH/WRITE): (a) each MFMA result is consumed immediately
// (C live = 4 not 20); (b) store unit vectors u[4][3] and fold the SH
// constants into the per-k multipliers (saves Y2r's 20 regs).
template <int HAS1>
__global__ __launch_bounds__(256, 3) void k_edge(float* __restrict__ ws, int l) {
  constexpr int K = HAS1 ? 5 : 3;   // s2==0 always; s1==0 in layer 0
  constexpr int N = K * 64;
  const int j = blockIdx.x & 511;
  const int half = blockIdx.x >> 9;
  const int t = threadIdx.x;
  const int lane = t & 63;
  const int wave = t >> 6;          // 0..3
  const int quad = lane >> 4;
  const int lo = lane & 15;

  __shared__ short Bhi[N * 40];     // [n][h], row stride 40 shorts (80B, 16B-aligned)
  __shared__ float red[4][64][9];

  {
    const float* we2 = ws + WS_WE2 + l * 32 * 384;
    for (int idx = t; idx < N * 32; idx += 256) {
      int n = idx >> 5, h = idx & 31;
      int kp = n >> 6, f = n & 63;
      Bhi[n * 40 + h] = f2b(we2[h * 384 + f * 6 + kp]);
    }
  }
  const float* pos = ws + WS_POS;
  const f32x4* xs = (const f32x4*)(ws + WS_XS);
  float we1v[8], be1v[8];
  #pragma unroll
  for (int i = 0; i < 8; ++i) {
    we1v[i] = ws[WS_WE1 + l * 32 + quad * 8 + i];
    be1v[i] = ws[WS_BE1 + l * 32 + quad * 8 + i];
  }
  const float pjx = pos[j * 3 + 0], pjy = pos[j * 3 + 1], pjz = pos[j * 3 + 2];

  const float s3 = 1.7320508075688772f;   // sqrt(3)
  const float s5h = 1.118033988749895f;   // 0.5*sqrt(5)
  const float s15 = 3.872983346207417f;   // sqrt(15)
  const float s15h = 1.9364916731037085f; // 0.5*sqrt(15)

  float acc[9][4] = {};  // [c][ft] — accumulators (AGPR-resident)
  __syncthreads();

  #pragma unroll 1
  for (int st = wave; st < 16; st += 4) {
    const int stile = half * 16 + st;
    // ---- A fragment: he for sender m=lo, k=quad*8+i ----
    bf16x8 af;
    {
      int ida = stile * 16 + lo;
      int ia = ida + (ida >= j);
      if (ia > 511) ia = 511;
      float pix = pos[ia * 3 + 0], piy = pos[ia * 3 + 1], piz = pos[ia * 3 + 2];
      float vx = pjx - pix, vy = pjy - piy, vz = pjz - piz;
      float r = sqrtf(vx * vx + vy * vy + vz * vz);
      #pragma unroll
      for (int i = 0; i < 8; ++i) {
        float x = r * we1v[i] + be1v[i];
        float he = x / (1.f + __expf(-x));
        af[i] = f2b(he);
      }
    }
    // ---- unit vectors + indices for this quad's 4 row-senders ----
    float ur[4][3];
    int ir[4];
    bool vld[4];
    #pragma unroll
    for (int r4 = 0; r4 < 4; ++r4) {
      int idx = stile * 16 + quad * 4 + r4;
      vld[r4] = idx < NS;
      int i = idx + (idx >= j);
      if (i > 511) i = 511;
      ir[r4] = i;
      float pix = pos[i * 3 + 0], piy = pos[i * 3 + 1], piz = pos[i * 3 + 2];
      float vx = pjx - pix, vy = pjy - piy, vz = pjz - piz;
      float r2 = vx * vx + vy * vy + vz * vz;
      float rinv = r2 > 0.f ? rsqrtf(r2) : 0.f;
      ur[r4][0] = vx * rinv; ur[r4][1] = vy * rinv; ur[r4][2] = vz * rinv;
    }
    // ---- per f-subtile: loads, then K MFMAs consumed immediately ----
    #pragma unroll
    for (int ft = 0; ft < 4; ++ft) {
      int fcol = ft * 16 + lo;
      f32x4 xv[4];
      #pragma unroll
      for (int r4 = 0; r4 < 4; ++r4) xv[r4] = xs[ir[r4] * 64 + fcol];
      const short* Bp = &Bhi[fcol * 40 + quad * 8];
      // kp0: acc0 += w0*s0
      {
        f32x4 c = {0.f, 0.f, 0.f, 0.f};
        c = __builtin_amdgcn_mfma_f32_16x16x32_bf16(af, *(const bf16x8*)(Bp), c, 0, 0, 0);
        #pragma unroll
        for (int r4 = 0; r4 < 4; ++r4)
          if (vld[r4]) acc[0][ft] += c[r4] * xv[r4].x;
      }
      // kp1: acc1..3 += w1*s0*Y1 = (w1*s0*s3)*u
      {
        f32x4 c = {0.f, 0.f, 0.f, 0.f};
        c = __builtin_amdgcn_mfma_f32_16x16x32_bf16(af, *(const bf16x8*)(Bp + 64 * 40), c, 0, 0, 0);
        #pragma unroll
        for (int r4 = 0; r4 < 4; ++r4)
          if (vld[r4]) {
            float tt = c[r4] * xv[r4].x * s3;
            acc[1][ft] += tt * ur[r4][0];
            acc[2][ft] += tt * ur[r4][1];
            acc[3][ft] += tt * ur[r4][2];
          }
      }
      // kp2: acc4..8 += w2*s0*Y2(u)
      {
        f32x4 c = {0.f, 0.f, 0.f, 0.f};
        c = __builtin_amdgcn_mfma_f32_16x16x32_bf16(af, *(const bf16x8*)(Bp + 128 * 40), c, 0, 0, 0);
        #pragma unroll
        for (int r4 = 0; r4 < 4; ++r4)
          if (vld[r4]) {
            float tt = c[r4] * xv[r4].x;
            float ux = ur[r4][0], uy = ur[r4][1], uz = ur[r4][2];
            float t15 = tt * s15;
            acc[4][ft] += t15 * ux * uy;
            acc[5][ft] += t15 * uy * uz;
            acc[6][ft] += (tt * s5h) * (3.f * uz * uz - 1.f);
            acc[7][ft] += t15 * ux * uz;
            acc[8][ft] += (tt * s15h) * (ux * ux - uy * uy);
          }
      }
      if (HAS1) {
        // kp3: acc0 += w3*(s1·Y1) = (w3*s3)*(s1·u)
        {
          f32x4 c = {0.f, 0.f, 0.f, 0.f};
          c = __builtin_amdgcn_mfma_f32_16x16x32_bf16(af, *(const bf16x8*)(Bp + 192 * 40), c, 0, 0, 0);
          #pragma unroll
          for (int r4 = 0; r4 < 4; ++r4)
            if (vld[r4]) {
              float d = xv[r4].y * ur[r4][0] + xv[r4].z * ur[r4][1] +
                        xv[r4].w * ur[r4][2];
              acc[0][ft] += (c[r4] * s3) * d;
            }
        }
        // kp4: acc1..3 += w4*cross(s1,Y1) = (w4*s3)*cross(s1,u)
        {
          f32x4 c = {0.f, 0.f, 0.f, 0.f};
          c = __builtin_amdgcn_mfma_f32_16x16x32_bf16(af, *(const bf16x8*)(Bp + 256 * 40), c, 0, 0, 0);
          #pragma unroll
          for (int r4 = 0; r4 < 4; ++r4)
            if (vld[r4]) {
              float w4 = c[r4] * s3;
              float s1x = xv[r4].y, s1y = xv[r4].z, s1z = xv[r4].w;
              acc[1][ft] += w4 * (s1y * ur[r4][2] - s1z * ur[r4][1]);
              acc[2][ft] += w4 * (s1z * ur[r4][0] - s1x * ur[r4][2]);
              acc[3][ft] += w4 * (s1x * ur[r4][1] - s1y * ur[r4][0]);
            }
        }
      }
    }
  }

  // ---- reduce over quads (butterfly), then over 4 waves (LDS) ----
  #pragma unroll
  for (int c = 0; c < 9; ++c)
    #pragma unroll
    for (int ft = 0; ft < 4; ++ft) {
      float v = acc[c][ft];
      v += __shfl_xor(v, 16);
      v += __shfl_xor(v, 32);
      acc[c][ft] = v;
    }
  if (quad == 0) {
    #pragma unroll
    for (int c = 0; c < 9; ++c)
      #pragma unroll
      for (int ft = 0; ft < 4; ++ft)
        red[wave][ft * 16 + lo][c] = acc[c][ft];
  }
  __syncthreads();
  for (int o = t; o < 576; o += 256) {
    int f = o / 9, c = o % 9;
    float s = red[0][f][c] + red[1][f][c] + red[2][f][c] + red[3][f][c];
    ws[WS_A + (half * NN + j) * 576 + f * 9 + c] = s;  // partial (unscaled)
  }
}

// ---------------- node update (+ fused layer-1 node linear for L=0) ----------------
template <int L>
__global__ __launch_bounds__(64) void k_node(const int* __restrict__ nodef,
                                             float* __restrict__ ws,
                                             void* __restrict__ out) {
  int n = blockIdx.x, f = threadIdx.x;
  const float* Ap0 = ws + WS_A + n * 576 + f * 9;
  const float* Ap1 = Ap0 + NN * 576;
  float a[9];
  #pragma unroll
  for (int c = 0; c < 9; ++c) a[c] = (Ap0[c] + Ap1[c]) * (1.f / 511.f);
  int sp = nodef[n] - 1;
  const float* w0p = ws + WS_WP0 + ((L * 5 + sp) * 64 + f) * 6;
  const float* w1p = ws + WS_WP1 + ((L * 5 + sp) * 64 + f) * 3;
  float A0 = a[0];
  float n1 = a[1] * a[1] + a[2] * a[2] + a[3] * a[3];
  float n2 = a[4] * a[4] + a[5] * a[5] + a[6] * a[6] + a[7] * a[7] + a[8] * a[8];
  float A02 = A0 * A0;
  float out0 = w0p[0] * A0 + w0p[1] * A02 + w0p[2] * A02 * A0 +
               w0p[3] * n1 + w0p[4] * n2 + w0p[5] * A0 * n1;
  float gp = w1p[0] + w1p[1] * A0 + w1p[2] * A02;
  float o1x = gp * a[1], o1y = gp * a[2], o1z = gp * a[3];

  __shared__ float s0l[64];
  __shared__ float o1l[3][64];
  __shared__ float hl[64];
  s0l[f] = out0;
  if (L == 0) { o1l[0][f] = o1x; o1l[1][f] = o1y; o1l[2][f] = o1z; }
  __syncthreads();

  if (L == 0) {
    // fused layer-1 node linear: XS[n][f] = (out0@W0, o1@W1 per comp)
    const float* W0 = ws + WS_WLIN + 3 * 4096;  // layer1, path0
    const float* W1 = ws + WS_WLIN + 4 * 4096;  // layer1, path1
    float b0 = 0.f, bx = 0.f, by = 0.f, bz = 0.f;
    #pragma unroll 8
    for (int q = 0; q < 64; ++q) {
      float w0 = W0[q * 64 + f];
      float w1 = W1[q * 64 + f];
      b0 += s0l[q] * w0;
      bx += o1l[0][q] * w1; by += o1l[1][q] * w1; bz += o1l[2][q] * w1;
    }
    f32x4 o = {b0, bx, by, bz};
    *(f32x4*)&ws[WS_XS + (n * 64 + f) * 4] = o;
  }

  // readout: hr = silu(out0 @ Wr1 + br1); gate = hr @ Wr2g
  float hacc = ws[WS_BR1 + L * 64 + f];
  const float* wr1 = ws + WS_WR1;
  #pragma unroll 8
  for (int q = 0; q < 64; ++q)
    hacc += s0l[q] * wr1[(L * 64 + q) * 64 + f];
  float hr = hacc / (1.f + __expf(-hacc));
  hl[f] = hr;
  __syncthreads();
  float gacc = 0.f;
  const float* wr2g = ws + WS_WR2G;
  #pragma unroll 8
  for (int m = 0; m < 64; ++m)
    gacc += hl[m] * wr2g[(L * 64 + m) * 64 + f];
  float px = gacc * o1x, py = gacc * o1y, pz = gacc * o1z;
  #pragma unroll
  for (int off = 32; off > 0; off >>= 1) {
    px += __shfl_down(px, off);
    py += __shfl_down(py, off);
    pz += __shfl_down(pz, off);
  }
  if (f == 0) {
    if (L == 0) {
      ws[WS_DELTA + n * 3 + 0] = px;
      ws[WS_DELTA + n * 3 + 1] = py;
      ws[WS_DELTA + n * 3 + 2] = pz;
      ws[WS_POS + n * 3 + 0] += px;
      ws[WS_POS + n * 3 + 1] += py;
      ws[WS_POS + n * 3 + 2] += pz;
    } else {
      float ox = ws[WS_DELTA + n * 3 + 0] + px;
      float oy = ws[WS_DELTA + n * 3 + 1] + py;
      float oz = ws[WS_DELTA + n * 3 + 2] + pz;
      int isf32 = ((const int*)ws)[0];
      if (isf32) {
        float* o = (float*)out;
        o[n * 3 + 0] = ox; o[n * 3 + 1] = oy; o[n * 3 + 2] = oz;
      } else {
        bf16* o = (bf16*)out;
        o[n * 3 + 0] = __float2bfloat16(ox);
        o[n * 3 + 1] = __float2bfloat16(oy);
        o[n * 3 + 2] = __float2bfloat16(oz);
      }
    }
  }
}

extern "C" void kernel_launch(void* const* d_in, const int* in_sizes, int n_in,
                              void* d_out, int out_size, void* d_ws, size_t ws_size,
                              hipStream_t stream) {
  const void* positions = d_in[0];
  const int*  nodef     = (const int*)d_in[1];
  const void* te        = d_in[2];
  const void* W_embed   = d_in[5];
  const void* b_embed   = d_in[6];
  const void* W_lin     = d_in[7];
  const void* W_e1      = d_in[8];
  const void* b_e1      = d_in[9];
  const void* W_e2      = d_in[10];
  const void* Wp0       = d_in[11];
  const void* Wp1       = d_in[12];
  const void* Wr1       = d_in[13];
  const void* br1       = d_in[14];
  const void* Wr2g      = d_in[16];
  float* ws = (float*)d_ws;
  (void)in_sizes; (void)n_in; (void)out_size; (void)ws_size;

  k_convert<<<dim3(296), dim3(256), 0, stream>>>(
      positions, te, W_embed, b_embed, W_lin, W_e1, b_e1, W_e2,
      Wp0, Wp1, Wr1, br1, Wr2g, W_embed, ws);
  k_pre<<<dim3(512), dim3(64), 0, stream>>>(nodef, ws);

  // layer 0 (s1 == 0)
  k_edge<0><<<dim3(1024), dim3(256), 0, stream>>>(ws, 0);
  k_node<0><<<dim3(512), dim3(64), 0, stream>>>(nodef, ws, d_out);

  // layer 1
  k_edge<1><<<dim3(1024), dim3(256), 0, stream>>>(ws, 1);
  k_node<1><<<dim3(512), dim3(64), 0, stream>>>(nodef, ws, d_out);
}

// Round 9
// 213.355 us; speedup vs baseline: 1.6619x; 1.6619x over previous
//
#include <hip/hip_runtime.h>
#include <hip/hip_bf16.h>

using bf16 = __hip_bfloat16;
using bf16x8 = __attribute__((ext_vector_type(8))) short;  // 8 bf16 (4 VGPRs)
using f32x4  = __attribute__((ext_vector_type(4))) float;

#define NN 512
#define NS 511

// ---------------- workspace layout (float offsets) ----------------
// slot 0 holds the dtype flag (int: 0 = bf16 inputs, 1 = f32 inputs)
enum : int {
  WS_POS   = 16,       // [512][3] positions (updated in-place after layer 0)
  WS_TE    = 1552,     // [32]
  WS_WEMB  = 1584,     // [37][64]
  WS_BEMB  = 3952,     // [64]
  WS_WLIN  = 4016,     // [2][3][64][64]
  WS_WE1   = 28592,    // [2][1][32]
  WS_BE1   = 28656,    // [2][32]
  WS_WE2   = 28720,    // [2][32][384]
  WS_WP0   = 53296,    // [2][5][64][6]
  WS_WP1   = 57136,    // [2][5][64][3]
  WS_WR1   = 59056,    // [2][64][64]
  WS_BR1   = 67248,    // [2][64]
  WS_WR2G  = 67376,    // [2][64][64]
  WS_DELTA = 75568,    // [512][3] layer-0 displacement
  WS_XS    = 208176,   // [512][64][4] interleaved (x0, x1x, x1y, x1z) — 16B aligned
  WS_A     = 339248,   // [2][512][64][9] partial sums (sender halves)
};                      // end = 929072 floats ~= 3.72 MB

// exact RNE float->bf16 bits (no NaN inputs here)
__device__ __forceinline__ short f2b(float x) {
  unsigned u = __builtin_bit_cast(unsigned, x);
  unsigned r = (u + 0x7fffu + ((u >> 16) & 1u)) >> 16;
  return (short)r;
}

// ---------------- convert (detect fused): everything -> fp32 in ws ----------------
__global__ __launch_bounds__(256) void k_convert(
    const void* p0, const void* p1, const void* p2, const void* p3,
    const void* p4, const void* p5, const void* p6, const void* p7,
    const void* p8, const void* p9, const void* p10, const void* p11,
    const void* p12, const void* wembed, float* __restrict__ ws) {
  int t = threadIdx.x;
  // per-block dtype detection on W_embed's first 256 bf16-view elements:
  // true-bf16 -> ~256 sane magnitudes; f32-misread -> ~170 sane.
  const bf16* wp = (const bf16*)wembed;
  float v = __bfloat162float(wp[t]);
  float a = fabsf(v);
  int sane = (v == v && a > 1e-8f && a < 1e4f) ? 1 : 0;
  int cnt = __syncthreads_count(sane);
  int isf32 = (cnt >= 240) ? 0 : 1;
  if (blockIdx.x == 0 && t == 0) ((int*)ws)[0] = isf32;
  int idx = blockIdx.x * 256 + t;
  if (idx >= 75552) return;
  const int C[14] = {0, 1536, 1568, 3936, 4000, 28576, 28640, 28704,
                     53280, 57120, 59040, 67232, 67360, 75552};
  int s = 0;
  #pragma unroll
  for (int k = 1; k < 14; ++k) if (idx >= C[k]) s = k;
  int off = idx - C[s];
  const void* src;
  switch (s) {
    case 0:  src = p0;  break;  case 1:  src = p1;  break;
    case 2:  src = p2;  break;  case 3:  src = p3;  break;
    case 4:  src = p4;  break;  case 5:  src = p5;  break;
    case 6:  src = p6;  break;  case 7:  src = p7;  break;
    case 8:  src = p8;  break;  case 9:  src = p9;  break;
    case 10: src = p10; break;  case 11: src = p11; break;
    default: src = p12; break;
  }
  float v2;
  if (isf32) v2 = ((const float*)src)[off];
  else       v2 = __bfloat162float(((const bf16*)src)[off]);
  ws[WS_POS + idx] = v2;
}

// ---------------- embedding + layer-0 node linear (fused) ----------------
__global__ __launch_bounds__(64) void k_pre(const int* __restrict__ nodef,
                                            float* __restrict__ ws) {
  int n = blockIdx.x, f = threadIdx.x;
  int sp = nodef[n] - 1;
  const float* wemb = ws + WS_WEMB;
  const float* te = ws + WS_TE;
  float h = ws[WS_BEMB + f] + wemb[sp * 64 + f];
  #pragma unroll 8
  for (int q = 0; q < 32; ++q)
    h += te[q] * wemb[(5 + q) * 64 + f];
  __shared__ float hl[64];
  hl[f] = h;
  __syncthreads();
  const float* W0 = ws + WS_WLIN;  // layer0, path0
  float a0 = 0.f;
  #pragma unroll 8
  for (int q = 0; q < 64; ++q)
    a0 += hl[q] * W0[q * 64 + f];
  f32x4 o = {a0, 0.f, 0.f, 0.f};
  *(f32x4*)&ws[WS_XS + (n * 64 + f) * 4] = o;
}

// ---------------- fused edge + aggregate (MFMA) ----------------
// Grid 1024 = 512 receivers x 2 sender-halves; 256 threads (4 waves).
// NOTE: __launch_bounds__ has NO min-waves arg. Declaring (256,3) capped the
// unified VGPR+AGPR budget at ~170 and forced ~1 KB/thread scratch spill
// (rounds 4-8: 90-200 MB FETCH/WRITE = spill round-trips to HBM at ~2 TB/s).
// Round 3's uncapped variant (VGPR 164) had FETCH 2.3 MB — no spill.
template <int HAS1>
__global__ __launch_bounds__(256) void k_edge(float* __restrict__ ws, int l) {
  constexpr int K = HAS1 ? 5 : 3;   // s2==0 always; s1==0 in layer 0
  constexpr int N = K * 64;
  const int j = blockIdx.x & 511;
  const int half = blockIdx.x >> 9;
  const int t = threadIdx.x;
  const int lane = t & 63;
  const int wave = t >> 6;          // 0..3
  const int quad = lane >> 4;
  const int lo = lane & 15;

  __shared__ short Bhi[N * 40];     // [n][h], row stride 40 shorts (80B, 16B-aligned)
  __shared__ float red[4][64][9];

  {
    const float* we2 = ws + WS_WE2 + l * 32 * 384;
    for (int idx = t; idx < N * 32; idx += 256) {
      int n = idx >> 5, h = idx & 31;
      int kp = n >> 6, f = n & 63;
      Bhi[n * 40 + h] = f2b(we2[h * 384 + f * 6 + kp]);
    }
  }
  const float* pos = ws + WS_POS;
  const f32x4* xs = (const f32x4*)(ws + WS_XS);
  float we1v[8], be1v[8];
  #pragma unroll
  for (int i = 0; i < 8; ++i) {
    we1v[i] = ws[WS_WE1 + l * 32 + quad * 8 + i];
    be1v[i] = ws[WS_BE1 + l * 32 + quad * 8 + i];
  }
  const float pjx = pos[j * 3 + 0], pjy = pos[j * 3 + 1], pjz = pos[j * 3 + 2];

  const float s3 = 1.7320508075688772f;
  const float s5h = 1.118033988749895f;    // 0.5*sqrt(5)
  const float s15 = 3.872983346207417f;
  const float s15h = 1.9364916731037085f;  // 0.5*sqrt(15)

  float acc[9][4] = {};  // [c][ft]
  __syncthreads();

  #pragma unroll 1
  for (int st = wave; st < 16; st += 4) {
    const int stile = half * 16 + st;
    // ---- A fragment: he for sender m=lo, k=quad*8+i ----
    bf16x8 af;
    {
      int ida = stile * 16 + lo;
      int ia = ida + (ida >= j);
      if (ia > 511) ia = 511;
      float pix = pos[ia * 3 + 0], piy = pos[ia * 3 + 1], piz = pos[ia * 3 + 2];
      float vx = pjx - pix, vy = pjy - piy, vz = pjz - piz;
      float r = sqrtf(vx * vx + vy * vy + vz * vz);
      #pragma unroll
      for (int i = 0; i < 8; ++i) {
        float x = r * we1v[i] + be1v[i];
        float he = x / (1.f + __expf(-x));
        af[i] = f2b(he);
      }
    }
    // ---- Y + indices for this quad's 4 row-senders ----
    float Y1r[4][3], Y2r[4][5];
    int ir[4];
    bool vld[4];
    #pragma unroll
    for (int r4 = 0; r4 < 4; ++r4) {
      int idx = stile * 16 + quad * 4 + r4;
      vld[r4] = idx < NS;
      int i = idx + (idx >= j);
      if (i > 511) i = 511;
      ir[r4] = i;
      float pix = pos[i * 3 + 0], piy = pos[i * 3 + 1], piz = pos[i * 3 + 2];
      float vx = pjx - pix, vy = pjy - piy, vz = pjz - piz;
      float r2 = vx * vx + vy * vy + vz * vz;
      float rinv = r2 > 0.f ? rsqrtf(r2) : 0.f;
      float ux = vx * rinv, uy = vy * rinv, uz = vz * rinv;
      Y1r[r4][0] = s3 * ux; Y1r[r4][1] = s3 * uy; Y1r[r4][2] = s3 * uz;
      Y2r[r4][0] = s15 * ux * uy;
      Y2r[r4][1] = s15 * uy * uz;
      Y2r[r4][2] = s5h * (3.f * uz * uz - 1.f);
      Y2r[r4][3] = s15 * ux * uz;
      Y2r[r4][4] = s15h * (ux * ux - uy * uy);
    }
    // ---- per f-subtile: loads, K MFMAs, then message math ----
    #pragma unroll
    for (int ft = 0; ft < 4; ++ft) {
      int fcol = ft * 16 + lo;
      f32x4 xv[4];
      #pragma unroll
      for (int r4 = 0; r4 < 4; ++r4) xv[r4] = xs[ir[r4] * 64 + fcol];
      f32x4 C[K];
      #pragma unroll
      for (int kp = 0; kp < K; ++kp) {
        const bf16x8 bh = *(const bf16x8*)&Bhi[(kp * 64 + fcol) * 40 + quad * 8];
        f32x4 c = {0.f, 0.f, 0.f, 0.f};
        C[kp] = __builtin_amdgcn_mfma_f32_16x16x32_bf16(af, bh, c, 0, 0, 0);
      }
      #pragma unroll
      for (int r4 = 0; r4 < 4; ++r4) {
        if (vld[r4]) {
          float s0 = xv[r4].x;
          float w0 = C[0][r4], w1 = C[1][r4], w2 = C[2][r4];
          if (HAS1) {
            float s1x = xv[r4].y, s1y = xv[r4].z, s1z = xv[r4].w;
            float w3 = C[3][r4], w4 = C[4][r4];
            float d1 = s1x * Y1r[r4][0] + s1y * Y1r[r4][1] + s1z * Y1r[r4][2];
            float cx = s1y * Y1r[r4][2] - s1z * Y1r[r4][1];
            float cy = s1z * Y1r[r4][0] - s1x * Y1r[r4][2];
            float cz = s1x * Y1r[r4][1] - s1y * Y1r[r4][0];
            acc[0][ft] += w0 * s0 + w3 * d1;
            float t1 = w1 * s0;
            acc[1][ft] += t1 * Y1r[r4][0] + w4 * cx;
            acc[2][ft] += t1 * Y1r[r4][1] + w4 * cy;
            acc[3][ft] += t1 * Y1r[r4][2] + w4 * cz;
          } else {
            acc[0][ft] += w0 * s0;
            float t1 = w1 * s0;
            acc[1][ft] += t1 * Y1r[r4][0];
            acc[2][ft] += t1 * Y1r[r4][1];
            acc[3][ft] += t1 * Y1r[r4][2];
          }
          float t2 = w2 * s0;
          acc[4][ft] += t2 * Y2r[r4][0];
          acc[5][ft] += t2 * Y2r[r4][1];
          acc[6][ft] += t2 * Y2r[r4][2];
          acc[7][ft] += t2 * Y2r[r4][3];
          acc[8][ft] += t2 * Y2r[r4][4];
        }
      }
    }
  }

  // ---- reduce over quads (butterfly), then over 4 waves (LDS) ----
  #pragma unroll
  for (int c = 0; c < 9; ++c)
    #pragma unroll
    for (int ft = 0; ft < 4; ++ft) {
      float v = acc[c][ft];
      v += __shfl_xor(v, 16);
      v += __shfl_xor(v, 32);
      acc[c][ft] = v;
    }
  if (quad == 0) {
    #pragma unroll
    for (int c = 0; c < 9; ++c)
      #pragma unroll
      for (int ft = 0; ft < 4; ++ft)
        red[wave][ft * 16 + lo][c] = acc[c][ft];
  }
  __syncthreads();
  for (int o = t; o < 576; o += 256) {
    int f = o / 9, c = o % 9;
    float s = red[0][f][c] + red[1][f][c] + red[2][f][c] + red[3][f][c];
    ws[WS_A + (half * NN + j) * 576 + f * 9 + c] = s;  // partial (unscaled)
  }
}

// ---------------- node update (+ fused layer-1 node linear for L=0) ----------------
template <int L>
__global__ __launch_bounds__(64) void k_node(const int* __restrict__ nodef,
                                             float* __restrict__ ws,
                                             void* __restrict__ out) {
  int n = blockIdx.x, f = threadIdx.x;
  const float* Ap0 = ws + WS_A + n * 576 + f * 9;
  const float* Ap1 = Ap0 + NN * 576;
  float a[9];
  #pragma unroll
  for (int c = 0; c < 9; ++c) a[c] = (Ap0[c] + Ap1[c]) * (1.f / 511.f);
  int sp = nodef[n] - 1;
  const float* w0p = ws + WS_WP0 + ((L * 5 + sp) * 64 + f) * 6;
  const float* w1p = ws + WS_WP1 + ((L * 5 + sp) * 64 + f) * 3;
  float A0 = a[0];
  float n1 = a[1] * a[1] + a[2] * a[2] + a[3] * a[3];
  float n2 = a[4] * a[4] + a[5] * a[5] + a[6] * a[6] + a[7] * a[7] + a[8] * a[8];
  float A02 = A0 * A0;
  float out0 = w0p[0] * A0 + w0p[1] * A02 + w0p[2] * A02 * A0 +
               w0p[3] * n1 + w0p[4] * n2 + w0p[5] * A0 * n1;
  float gp = w1p[0] + w1p[1] * A0 + w1p[2] * A02;
  float o1x = gp * a[1], o1y = gp * a[2], o1z = gp * a[3];

  __shared__ float s0l[64];
  __shared__ float o1l[3][64];
  __shared__ float hl[64];
  s0l[f] = out0;
  if (L == 0) { o1l[0][f] = o1x; o1l[1][f] = o1y; o1l[2][f] = o1z; }
  __syncthreads();

  if (L == 0) {
    // fused layer-1 node linear: XS[n][f] = (out0@W0, o1@W1 per comp)
    const float* W0 = ws + WS_WLIN + 3 * 4096;  // layer1, path0
    const float* W1 = ws + WS_WLIN + 4 * 4096;  // layer1, path1
    float b0 = 0.f, bx = 0.f, by = 0.f, bz = 0.f;
    #pragma unroll 8
    for (int q = 0; q < 64; ++q) {
      float w0 = W0[q * 64 + f];
      float w1 = W1[q * 64 + f];
      b0 += s0l[q] * w0;
      bx += o1l[0][q] * w1; by += o1l[1][q] * w1; bz += o1l[2][q] * w1;
    }
    f32x4 o = {b0, bx, by, bz};
    *(f32x4*)&ws[WS_XS + (n * 64 + f) * 4] = o;
  }

  // readout: hr = silu(out0 @ Wr1 + br1); gate = hr @ Wr2g
  float hacc = ws[WS_BR1 + L * 64 + f];
  const float* wr1 = ws + WS_WR1;
  #pragma unroll 8
  for (int q = 0; q < 64; ++q)
    hacc += s0l[q] * wr1[(L * 64 + q) * 64 + f];
  float hr = hacc / (1.f + __expf(-hacc));
  hl[f] = hr;
  __syncthreads();
  float gacc = 0.f;
  const float* wr2g = ws + WS_WR2G;
  #pragma unroll 8
  for (int m = 0; m < 64; ++m)
    gacc += hl[m] * wr2g[(L * 64 + m) * 64 + f];
  float px = gacc * o1x, py = gacc * o1y, pz = gacc * o1z;
  #pragma unroll
  for (int off = 32; off > 0; off >>= 1) {
    px += __shfl_down(px, off);
    py += __shfl_down(py, off);
    pz += __shfl_down(pz, off);
  }
  if (f == 0) {
    if (L == 0) {
      ws[WS_DELTA + n * 3 + 0] = px;
      ws[WS_DELTA + n * 3 + 1] = py;
      ws[WS_DELTA + n * 3 + 2] = pz;
      ws[WS_POS + n * 3 + 0] += px;
      ws[WS_POS + n * 3 + 1] += py;
      ws[WS_POS + n * 3 + 2] += pz;
    } else {
      float ox = ws[WS_DELTA + n * 3 + 0] + px;
      float oy = ws[WS_DELTA + n * 3 + 1] + py;
      float oz = ws[WS_DELTA + n * 3 + 2] + pz;
      int isf32 = ((const int*)ws)[0];
      if (isf32) {
        float* o = (float*)out;
        o[n * 3 + 0] = ox; o[n * 3 + 1] = oy; o[n * 3 + 2] = oz;
      } else {
        bf16* o = (bf16*)out;
        o[n * 3 + 0] = __float2bfloat16(ox);
        o[n * 3 + 1] = __float2bfloat16(oy);
        o[n * 3 + 2] = __float2bfloat16(oz);
      }
    }
  }
}

extern "C" void kernel_launch(void* const* d_in, const int* in_sizes, int n_in,
                              void* d_out, int out_size, void* d_ws, size_t ws_size,
                              hipStream_t stream) {
  const void* positions = d_in[0];
  const int*  nodef     = (const int*)d_in[1];
  const void* te        = d_in[2];
  const void* W_embed   = d_in[5];
  const void* b_embed   = d_in[6];
  const void* W_lin     = d_in[7];
  const void* W_e1      = d_in[8];
  const void* b_e1      = d_in[9];
  const void* W_e2      = d_in[10];
  const void* Wp0       = d_in[11];
  const void* Wp1       = d_in[12];
  const void* Wr1       = d_in[13];
  const void* br1       = d_in[14];
  const void* Wr2g      = d_in[16];
  float* ws = (float*)d_ws;
  (void)in_sizes; (void)n_in; (void)out_size; (void)ws_size;

  k_convert<<<dim3(296), dim3(256), 0, stream>>>(
      positions, te, W_embed, b_embed, W_lin, W_e1, b_e1, W_e2,
      Wp0, Wp1, Wr1, br1, Wr2g, W_embed, ws);
  k_pre<<<dim3(512), dim3(64), 0, stream>>>(nodef, ws);

  // layer 0 (s1 == 0)
  k_edge<0><<<dim3(1024), dim3(256), 0, stream>>>(ws, 0);
  k_node<0><<<dim3(512), dim3(64), 0, stream>>>(nodef, ws, d_out);

  // layer 1
  k_edge<1><<<dim3(1024), dim3(256), 0, stream>>>(ws, 1);
  k_node<1><<<dim3(512), dim3(64), 0, stream>>>(nodef, ws, d_out);
}

// Round 10
// 207.721 us; speedup vs baseline: 1.7070x; 1.0271x over previous
//
#include <hip/hip_runtime.h>
#include <hip/hip_bf16.h>

using bf16 = __hip_bfloat16;
using bf16x8 = __attribute__((ext_vector_type(8))) short;  // 8 bf16 (4 VGPRs)
using f32x4  = __attribute__((ext_vector_type(4))) float;

#define NN 512
#define NS 511

// ---------------- workspace layout (float offsets) ----------------
enum : int {
  WS_FLAG = 0,        // int: 0 = bf16 inputs, 1 = f32 inputs
  WS_POS  = 16,       // [512][3] positions (layer 0)
  WS_POS2 = 1552,     // [512][3] positions after layer-0 update (layer 1 reads)
  WS_DELTA= 3088,     // [512][3] layer-0 displacement
  WS_XS0  = 4624,     // [512][64][4] (x0,x1x,x1y,x1z) for layer 0 — 16B aligned
  WS_XS1  = 135696,   // [512][64][4] for layer 1
};                     // end = 266768 floats ~= 1.07 MB

// exact RNE float->bf16 bits (no NaN inputs here)
__device__ __forceinline__ short f2b(float x) {
  unsigned u = __builtin_bit_cast(unsigned, x);
  unsigned r = (u + 0x7fffu + ((u >> 16) & 1u)) >> 16;
  return (short)r;
}

// dtype-branched scalar load (branch, NOT select: f32-view OOB if input is bf16)
__device__ __forceinline__ float ld(const void* p, int i, int isf32) {
  if (isf32) return ((const float*)p)[i];
  return __bfloat162float(((const bf16*)p)[i]);
}

// ---------------- pre: detect + pos convert + embedding + layer-0 lin ----------------
__global__ __launch_bounds__(64) void k_pre(
    const void* __restrict__ positions, const int* __restrict__ nodef,
    const void* __restrict__ te, const void* __restrict__ W_embed,
    const void* __restrict__ b_embed, const void* __restrict__ W_lin,
    float* __restrict__ ws) {
  int n = blockIdx.x, f = threadIdx.x;
  // inline dtype detection on W_embed's first 256 bf16-view elements:
  // true-bf16 -> ~256 sane magnitudes; f32-misread -> ~170 sane.
  int cnt = 0;
  #pragma unroll
  for (int kq = 0; kq < 4; ++kq) {
    float v = __bfloat162float(((const bf16*)W_embed)[f + kq * 64]);
    float av = fabsf(v);
    cnt += (v == v && av > 1e-8f && av < 1e4f) ? 1 : 0;
  }
  #pragma unroll
  for (int off = 32; off > 0; off >>= 1) cnt += __shfl_down(cnt, off);
  int tot = __shfl(cnt, 0);
  int isf32 = (tot >= 240) ? 0 : 1;
  if (n == 0 && f == 0) ((int*)ws)[WS_FLAG] = isf32;

  if (f < 3) ws[WS_POS + n * 3 + f] = ld(positions, n * 3 + f, isf32);

  int sp = nodef[n] - 1;
  float h = ld(b_embed, f, isf32) + ld(W_embed, sp * 64 + f, isf32);
  #pragma unroll 8
  for (int q = 0; q < 32; ++q)
    h += ld(te, q, isf32) * ld(W_embed, (5 + q) * 64 + f, isf32);
  __shared__ float hl[64];
  hl[f] = h;
  __syncthreads();
  float a0 = 0.f;
  #pragma unroll 8
  for (int q = 0; q < 64; ++q)
    a0 += hl[q] * ld(W_lin, q * 64 + f, isf32);  // layer0, path0
  f32x4 o = {a0, 0.f, 0.f, 0.f};
  *(f32x4*)&ws[WS_XS0 + (n * 64 + f) * 4] = o;
}

// ---------------- fused edge + aggregate + node update ----------------
// One block per receiver j (grid 512); 256 threads (4 waves). Edge body is
// round-9's verbatim (proven: 128 VGPR, zero spill — NO min-waves in
// __launch_bounds__; a (256,3) cap forces ~1KB/thread scratch spill at HBM
// speed, rounds 4-8). After the A-reduce, wave 0 performs the node update
// (poly readout + next-layer lin + gated pos update) for node j.
// Cross-layer state is double-buffered (POS->POS2, XS0->XS1): block j writes
// only its own node's next-layer slots, read in the NEXT dispatch.
template <int L>
__global__ __launch_bounds__(256) void k_edgenode(
    const int* __restrict__ nodef, const void* __restrict__ W_lin,
    const void* __restrict__ W_e1, const void* __restrict__ b_e1,
    const void* __restrict__ W_e2, const void* __restrict__ Wp0,
    const void* __restrict__ Wp1, const void* __restrict__ Wr1,
    const void* __restrict__ br1, const void* __restrict__ Wr2g,
    float* __restrict__ ws, void* __restrict__ out) {
  constexpr int HAS1 = L;          // s1==0 in layer 0
  constexpr int K = HAS1 ? 5 : 3;  // s2==0 always
  constexpr int N = K * 64;
  const int j = blockIdx.x;
  const int t = threadIdx.x;
  const int lane = t & 63;
  const int wave = t >> 6;          // 0..3
  const int quad = lane >> 4;
  const int lo = lane & 15;

  __shared__ short Bhi[N * 40];     // [n][h], row stride 40 shorts (80B, 16B-aligned)
  __shared__ float red[4][64][9];
  __shared__ float Af[64][9];
  __shared__ float s0l[64];
  __shared__ float o1l[3][64];
  __shared__ float hl[64];

  const int isf32 = ((const int*)ws)[WS_FLAG];

  {  // stage W2 slice -> LDS bf16 (direct bit copy if input already bf16)
    for (int idx = t; idx < N * 32; idx += 256) {
      int n = idx >> 5, h = idx & 31;
      int kp = n >> 6, f = n & 63;
      int src = (L * 32 + h) * 384 + f * 6 + kp;
      short bits;
      if (isf32) bits = f2b(((const float*)W_e2)[src]);
      else       bits = ((const short*)W_e2)[src];
      Bhi[n * 40 + h] = bits;
    }
  }
  const float* pos = ws + (L ? WS_POS2 : WS_POS);
  const f32x4* xs = (const f32x4*)(ws + (L ? WS_XS1 : WS_XS0));
  float we1v[8], be1v[8];
  #pragma unroll
  for (int i = 0; i < 8; ++i) {
    we1v[i] = ld(W_e1, L * 32 + quad * 8 + i, isf32);
    be1v[i] = ld(b_e1, L * 32 + quad * 8 + i, isf32);
  }
  const float pjx = pos[j * 3 + 0], pjy = pos[j * 3 + 1], pjz = pos[j * 3 + 2];

  const float s3 = 1.7320508075688772f;
  const float s5h = 1.118033988749895f;    // 0.5*sqrt(5)
  const float s15 = 3.872983346207417f;
  const float s15h = 1.9364916731037085f;  // 0.5*sqrt(15)

  float acc[9][4] = {};  // [c][ft]
  __syncthreads();

  #pragma unroll 1
  for (int stile = wave; stile < 32; stile += 4) {
    // ---- A fragment: he for sender m=lo, k=quad*8+i ----
    bf16x8 af;
    {
      int ida = stile * 16 + lo;
      int ia = ida + (ida >= j);
      if (ia > 511) ia = 511;
      float pix = pos[ia * 3 + 0], piy = pos[ia * 3 + 1], piz = pos[ia * 3 + 2];
      float vx = pjx - pix, vy = pjy - piy, vz = pjz - piz;
      float r = sqrtf(vx * vx + vy * vy + vz * vz);
      #pragma unroll
      for (int i = 0; i < 8; ++i) {
        float x = r * we1v[i] + be1v[i];
        float he = x / (1.f + __expf(-x));
        af[i] = f2b(he);
      }
    }
    // ---- Y + indices for this quad's 4 row-senders ----
    float Y1r[4][3], Y2r[4][5];
    int ir[4];
    bool vld[4];
    #pragma unroll
    for (int r4 = 0; r4 < 4; ++r4) {
      int idx = stile * 16 + quad * 4 + r4;
      vld[r4] = idx < NS;
      int i = idx + (idx >= j);
      if (i > 511) i = 511;
      ir[r4] = i;
      float pix = pos[i * 3 + 0], piy = pos[i * 3 + 1], piz = pos[i * 3 + 2];
      float vx = pjx - pix, vy = pjy - piy, vz = pjz - piz;
      float r2 = vx * vx + vy * vy + vz * vz;
      float rinv = r2 > 0.f ? rsqrtf(r2) : 0.f;
      float ux = vx * rinv, uy = vy * rinv, uz = vz * rinv;
      Y1r[r4][0] = s3 * ux; Y1r[r4][1] = s3 * uy; Y1r[r4][2] = s3 * uz;
      Y2r[r4][0] = s15 * ux * uy;
      Y2r[r4][1] = s15 * uy * uz;
      Y2r[r4][2] = s5h * (3.f * uz * uz - 1.f);
      Y2r[r4][3] = s15 * ux * uz;
      Y2r[r4][4] = s15h * (ux * ux - uy * uy);
    }
    // ---- per f-subtile: loads, K MFMAs, then message math ----
    #pragma unroll
    for (int ft = 0; ft < 4; ++ft) {
      int fcol = ft * 16 + lo;
      f32x4 xv[4];
      #pragma unroll
      for (int r4 = 0; r4 < 4; ++r4) xv[r4] = xs[ir[r4] * 64 + fcol];
      f32x4 C[K];
      #pragma unroll
      for (int kp = 0; kp < K; ++kp) {
        const bf16x8 bh = *(const bf16x8*)&Bhi[(kp * 64 + fcol) * 40 + quad * 8];
        f32x4 c = {0.f, 0.f, 0.f, 0.f};
        C[kp] = __builtin_amdgcn_mfma_f32_16x16x32_bf16(af, bh, c, 0, 0, 0);
      }
      #pragma unroll
      for (int r4 = 0; r4 < 4; ++r4) {
        if (vld[r4]) {
          float s0 = xv[r4].x;
          float w0 = C[0][r4], w1 = C[1][r4], w2 = C[2][r4];
          if (HAS1) {
            float s1x = xv[r4].y, s1y = xv[r4].z, s1z = xv[r4].w;
            float w3 = C[3][r4], w4 = C[4][r4];
            float d1 = s1x * Y1r[r4][0] + s1y * Y1r[r4][1] + s1z * Y1r[r4][2];
            float cx = s1y * Y1r[r4][2] - s1z * Y1r[r4][1];
            float cy = s1z * Y1r[r4][0] - s1x * Y1r[r4][2];
            float cz = s1x * Y1r[r4][1] - s1y * Y1r[r4][0];
            acc[0][ft] += w0 * s0 + w3 * d1;
            float t1 = w1 * s0;
            acc[1][ft] += t1 * Y1r[r4][0] + w4 * cx;
            acc[2][ft] += t1 * Y1r[r4][1] + w4 * cy;
            acc[3][ft] += t1 * Y1r[r4][2] + w4 * cz;
          } else {
            acc[0][ft] += w0 * s0;
            float t1 = w1 * s0;
            acc[1][ft] += t1 * Y1r[r4][0];
            acc[2][ft] += t1 * Y1r[r4][1];
            acc[3][ft] += t1 * Y1r[r4][2];
          }
          float t2 = w2 * s0;
          acc[4][ft] += t2 * Y2r[r4][0];
          acc[5][ft] += t2 * Y2r[r4][1];
          acc[6][ft] += t2 * Y2r[r4][2];
          acc[7][ft] += t2 * Y2r[r4][3];
          acc[8][ft] += t2 * Y2r[r4][4];
        }
      }
    }
  }

  // ---- reduce over quads (butterfly), then over 4 waves (LDS) -> Af ----
  #pragma unroll
  for (int c = 0; c < 9; ++c)
    #pragma unroll
    for (int ft = 0; ft < 4; ++ft) {
      float v = acc[c][ft];
      v += __shfl_xor(v, 16);
      v += __shfl_xor(v, 32);
      acc[c][ft] = v;
    }
  if (quad == 0) {
    #pragma unroll
    for (int c = 0; c < 9; ++c)
      #pragma unroll
      for (int ft = 0; ft < 4; ++ft)
        red[wave][ft * 16 + lo][c] = acc[c][ft];
  }
  __syncthreads();
  for (int o = t; o < 576; o += 256) {
    int f = o / 9, c = o % 9;
    Af[f][c] = (red[0][f][c] + red[1][f][c] + red[2][f][c] + red[3][f][c]) *
               (1.f / 511.f);
  }
  __syncthreads();

  // ---- node-update tail (wave 0; other waves ride the barriers) ----
  float out0 = 0.f, o1x = 0.f, o1y = 0.f, o1z = 0.f;
  if (t < 64) {
    int f = t;
    float a[9];
    #pragma unroll
    for (int c = 0; c < 9; ++c) a[c] = Af[f][c];
    int sp = nodef[j] - 1;
    int b0i = ((L * 5 + sp) * 64 + f) * 6;
    int b1i = ((L * 5 + sp) * 64 + f) * 3;
    float A0 = a[0];
    float n1 = a[1] * a[1] + a[2] * a[2] + a[3] * a[3];
    float n2 = a[4] * a[4] + a[5] * a[5] + a[6] * a[6] + a[7] * a[7] + a[8] * a[8];
    float A02 = A0 * A0;
    out0 = ld(Wp0, b0i + 0, isf32) * A0 + ld(Wp0, b0i + 1, isf32) * A02 +
           ld(Wp0, b0i + 2, isf32) * A02 * A0 + ld(Wp0, b0i + 3, isf32) * n1 +
           ld(Wp0, b0i + 4, isf32) * n2 + ld(Wp0, b0i + 5, isf32) * A0 * n1;
    float gp = ld(Wp1, b1i + 0, isf32) + ld(Wp1, b1i + 1, isf32) * A0 +
               ld(Wp1, b1i + 2, isf32) * A02;
    o1x = gp * a[1]; o1y = gp * a[2]; o1z = gp * a[3];
    s0l[f] = out0;
    if (L == 0) { o1l[0][f] = o1x; o1l[1][f] = o1y; o1l[2][f] = o1z; }
  }
  __syncthreads();
  if (t < 64) {
    int f = t;
    if (L == 0) {
      // next-layer node linear into XS1 (read in the next dispatch)
      float b0 = 0.f, bx = 0.f, by = 0.f, bz = 0.f;
      #pragma unroll 8
      for (int q = 0; q < 64; ++q) {
        float w0 = ld(W_lin, 3 * 4096 + q * 64 + f, isf32);  // layer1, path0
        float w1 = ld(W_lin, 4 * 4096 + q * 64 + f, isf32);  // layer1, path1
        b0 += s0l[q] * w0;
        bx += o1l[0][q] * w1; by += o1l[1][q] * w1; bz += o1l[2][q] * w1;
      }
      f32x4 o = {b0, bx, by, bz};
      *(f32x4*)&ws[WS_XS1 + (j * 64 + f) * 4] = o;
    }
    float hacc = ld(br1, L * 64 + f, isf32);
    #pragma unroll 8
    for (int q = 0; q < 64; ++q)
      hacc += s0l[q] * ld(Wr1, (L * 64 + q) * 64 + f, isf32);
    hl[f] = hacc / (1.f + __expf(-hacc));
  }
  __syncthreads();
  if (t < 64) {
    int f = t;
    float gacc = 0.f;
    #pragma unroll 8
    for (int m = 0; m < 64; ++m)
      gacc += hl[m] * ld(Wr2g, (L * 64 + m) * 64 + f, isf32);
    float px = gacc * o1x, py = gacc * o1y, pz = gacc * o1z;
    #pragma unroll
    for (int off = 32; off > 0; off >>= 1) {
      px += __shfl_down(px, off);
      py += __shfl_down(py, off);
      pz += __shfl_down(pz, off);
    }
    if (f == 0) {
      if (L == 0) {
        ws[WS_DELTA + j * 3 + 0] = px;
        ws[WS_DELTA + j * 3 + 1] = py;
        ws[WS_DELTA + j * 3 + 2] = pz;
        ws[WS_POS2 + j * 3 + 0] = pos[j * 3 + 0] + px;
        ws[WS_POS2 + j * 3 + 1] = pos[j * 3 + 1] + py;
        ws[WS_POS2 + j * 3 + 2] = pos[j * 3 + 2] + pz;
      } else {
        float ox = ws[WS_DELTA + j * 3 + 0] + px;
        float oy = ws[WS_DELTA + j * 3 + 1] + py;
        float oz = ws[WS_DELTA + j * 3 + 2] + pz;
        if (isf32) {
          float* o = (float*)out;
          o[j * 3 + 0] = ox; o[j * 3 + 1] = oy; o[j * 3 + 2] = oz;
        } else {
          bf16* o = (bf16*)out;
          o[j * 3 + 0] = __float2bfloat16(ox);
          o[j * 3 + 1] = __float2bfloat16(oy);
          o[j * 3 + 2] = __float2bfloat16(oz);
        }
      }
    }
  }
}

extern "C" void kernel_launch(void* const* d_in, const int* in_sizes, int n_in,
                              void* d_out, int out_size, void* d_ws, size_t ws_size,
                              hipStream_t stream) {
  const void* positions = d_in[0];
  const int*  nodef     = (const int*)d_in[1];
  const void* te        = d_in[2];
  const void* W_embed   = d_in[5];
  const void* b_embed   = d_in[6];
  const void* W_lin     = d_in[7];
  const void* W_e1      = d_in[8];
  const void* b_e1      = d_in[9];
  const void* W_e2      = d_in[10];
  const void* Wp0       = d_in[11];
  const void* Wp1       = d_in[12];
  const void* Wr1       = d_in[13];
  const void* br1       = d_in[14];
  const void* Wr2g      = d_in[16];
  float* ws = (float*)d_ws;
  (void)in_sizes; (void)n_in; (void)out_size; (void)ws_size;

  k_pre<<<dim3(512), dim3(64), 0, stream>>>(positions, nodef, te, W_embed,
                                            b_embed, W_lin, ws);
  k_edgenode<0><<<dim3(512), dim3(256), 0, stream>>>(
      nodef, W_lin, W_e1, b_e1, W_e2, Wp0, Wp1, Wr1, br1, Wr2g, ws, d_out);
  k_edgenode<1><<<dim3(512), dim3(256), 0, stream>>>(
      nodef, W_lin, W_e1, b_e1, W_e2, Wp0, Wp1, Wr1, br1, Wr2g, ws, d_out);
}